// Round 1
// baseline (590.947 us; speedup 1.0000x reference)
//
#include <hip/hip_runtime.h>
#include <hip/hip_bf16.h>
#include <cstdint>

typedef unsigned short u16;
typedef __attribute__((ext_vector_type(8))) short bf16x8;
typedef __attribute__((ext_vector_type(4))) float f32x4;

#define BB 64
#define EE 1024
#define HH 1024
#define LLEN 512
#define VV 50257
#define EH 2048
#define H3 3072
#define NCHUNK 16
#define CHUNK 3142  // ceil(50257/16)

__device__ __forceinline__ u16 f2b(float f) {
  union { float f; uint32_t i; } v; v.f = f;
  uint32_t i = v.i;
  uint32_t r = (i + 0x7FFFu + ((i >> 16) & 1u)) >> 16;  // RNE
  return (u16)r;
}
__device__ __forceinline__ bf16x8 cvt8(float4 a, float4 b) {
  bf16x8 o;
  o[0] = (short)f2b(a.x); o[1] = (short)f2b(a.y); o[2] = (short)f2b(a.z); o[3] = (short)f2b(a.w);
  o[4] = (short)f2b(b.x); o[5] = (short)f2b(b.y); o[6] = (short)f2b(b.z); o[7] = (short)f2b(b.w);
  return o;
}

// ---- embedding gather + bf16 staging: cat1=[emb|hid], cat2[:, :E]=emb, hbf=bf16(hid)
// vectorized: 256 threads * 4 floats = 1024 = E
__global__ void prep_k(const int* __restrict__ ids, const float* __restrict__ embW,
                       const float* __restrict__ hid, u16* __restrict__ cat1,
                       u16* __restrict__ cat2, u16* __restrict__ hbf) {
  int b = blockIdx.x, t = threadIdx.x;
  int e = t * 4;
  const float* er = embW + (size_t)ids[b] * EE;
  float4 ev = *(const float4*)(er + e);
  float4 hv = *(const float4*)(hid + b * HH + e);
  ushort4 eb = { f2b(ev.x), f2b(ev.y), f2b(ev.z), f2b(ev.w) };
  ushort4 hb = { f2b(hv.x), f2b(hv.y), f2b(hv.z), f2b(hv.w) };
  *(ushort4*)(cat1 + b * EH + e) = eb;
  *(ushort4*)(cat2 + b * EH + e) = eb;
  *(ushort4*)(cat1 + b * EH + EE + e) = hb;
  *(ushort4*)(hbf + b * HH + e) = hb;
}

// ---- MFMA bf16 GEMM body: C[64,N] = A_bf16[64,K] * bf16(W_f32[N,K])^T
// MODE 0: fp32 partials [ksplit][64][N] (by = k-split index)
// MODE 1: direct fp32 store with fp32 bias (by == 0, kpc = K/32)
template<int WN, int MODE>
__device__ __forceinline__ void gemm_body(
    const u16* __restrict__ A, const float* __restrict__ W,
    float* __restrict__ outp, const float* __restrict__ bias,
    int N, int K, int kpc, int bx, int by) {
  const int lane = threadIdx.x & 63;
  const int wv = threadIdx.x >> 6;
  const int ml = lane & 15;   // A: m index / W: n index / C: col
  const int q  = lane >> 4;   // k quad
  const int n0 = bx * (64 * WN) + wv * (16 * WN);
  const int kc0 = by * kpc;
  f32x4 acc[4][WN];
#pragma unroll
  for (int bt = 0; bt < 4; ++bt)
#pragma unroll
    for (int w = 0; w < WN; ++w) acc[bt][w] = (f32x4){0.f, 0.f, 0.f, 0.f};

  for (int kc = kc0; kc < kc0 + kpc; ++kc) {
    const int kk = kc * 32 + q * 8;
    bf16x8 af[4];
#pragma unroll
    for (int bt = 0; bt < 4; ++bt)
      af[bt] = *(const bf16x8*)(A + (size_t)(bt * 16 + ml) * K + kk);
    bf16x8 wf[WN];
#pragma unroll
    for (int w = 0; w < WN; ++w) {
      int r = n0 + w * 16 + ml;
      int rc = r < N ? r : N - 1;  // clamp: OOB lanes never store, value irrelevant
      const float4* wp = (const float4*)(W + (size_t)rc * K + kk);
      wf[w] = cvt8(wp[0], wp[1]);
    }
#pragma unroll
    for (int bt = 0; bt < 4; ++bt)
#pragma unroll
      for (int w = 0; w < WN; ++w)
        acc[bt][w] = __builtin_amdgcn_mfma_f32_16x16x32_bf16(af[bt], wf[w], acc[bt][w], 0, 0, 0);
  }

#pragma unroll
  for (int bt = 0; bt < 4; ++bt)
#pragma unroll
    for (int w = 0; w < WN; ++w) {
      int n = n0 + w * 16 + ml;
#pragma unroll
      for (int r = 0; r < 4; ++r) {
        int b = bt * 16 + q * 4 + r;  // C row = (lane>>4)*4 + reg within m-tile
        if (MODE == 0) {
          outp[((size_t)by * 64 + b) * N + n] = acc[bt][w][r];
        } else {
          if (n < N)
            outp[(size_t)b * N + n] = acc[bt][w][r] + bias[n];
        }
      }
    }
}

template<int WN, int MODE>
__global__ __launch_bounds__(256) void gemm_k(
    const u16* __restrict__ A, const float* __restrict__ W,
    float* __restrict__ outp, const float* __restrict__ bias,
    int N, int K, int kpc) {
  gemm_body<WN, MODE>(A, W, outp, bias, N, K, kpc, blockIdx.x, blockIdx.y);
}

// ---- fused GRU input+hidden GEMMs (independent; z picks which)
__global__ __launch_bounds__(256) void gru_gemm_k(
    const u16* __restrict__ xbf, const u16* __restrict__ hbf,
    const float* __restrict__ Wih, const float* __restrict__ Whh,
    float* __restrict__ Ugi, float* __restrict__ Ugh) {
  if (blockIdx.z == 0)
    gemm_body<2, 0>(xbf, Wih, Ugi, (const float*)nullptr, H3, HH, 8, blockIdx.x, blockIdx.y);
  else
    gemm_body<2, 0>(hbf, Whh, Ugh, (const float*)nullptr, H3, HH, 8, blockIdx.x, blockIdx.y);
}

// ---- k-split reduce + bias + optional relu; fp32 and/or bf16 out (comb path)
__global__ void reduce_k(const float* __restrict__ part, int ks, int count, int N,
                         const float* __restrict__ bias, int relu,
                         float* __restrict__ outF, u16* __restrict__ outB) {
  int idx = blockIdx.x * 256 + threadIdx.x;
  if (idx >= count) return;
  float s = 0.f;
  for (int k = 0; k < ks; ++k) s += part[(size_t)k * count + idx];
  int n = idx % N;
  s += bias[n];
  if (relu) s = fmaxf(s, 0.f);
  if (outF) outF[idx] = s;
  if (outB) outB[idx] = f2b(s);
}

// ---- fused: 32-way k-split reduce of attention scores + bias + softmax over L=512
__global__ void softmax_fused_k(const float* __restrict__ U, const float* __restrict__ bias,
                                float* __restrict__ aw) {
  int b = blockIdx.x, t = threadIdx.x;
  __shared__ float sd[256];
  float v0 = bias[t], v1 = bias[256 + t];
#pragma unroll 8
  for (int k = 0; k < 32; ++k) {
    const float* row = U + ((size_t)(k * 64 + b)) * LLEN;
    v0 += row[t];
    v1 += row[256 + t];
  }
  float m = fmaxf(v0, v1);
  sd[t] = m; __syncthreads();
  for (int st = 128; st > 0; st >>= 1) { if (t < st) sd[t] = fmaxf(sd[t], sd[t + st]); __syncthreads(); }
  m = sd[0]; __syncthreads();
  float e0 = __expf(v0 - m), e1 = __expf(v1 - m);
  sd[t] = e0 + e1; __syncthreads();
  for (int st = 128; st > 0; st >>= 1) { if (t < st) sd[t] += sd[t + st]; __syncthreads(); }
  float inv = 1.0f / sd[0];
  aw[b * LLEN + t] = e0 * inv;
  aw[b * LLEN + 256 + t] = e1 * inv;
}

// ---- attn_applied partials: block = (b, l-chunk of 16); 2048 blocks, 16-deep load pipe
__global__ void attn_part_k(const float* __restrict__ aw, const float* __restrict__ enc,
                            float* __restrict__ part) {
  int bid = blockIdx.x;
  int b = bid >> 5, lc = bid & 31;
  int d0 = threadIdx.x * 4;
  const float* base = enc + ((size_t)b * LLEN + lc * 16) * HH + d0;
  const float* awp = aw + b * LLEN + lc * 16;
  float a0 = 0, a1 = 0, a2 = 0, a3 = 0;
#pragma unroll
  for (int l = 0; l < 16; ++l) {
    float w = awp[l];  // wave-uniform -> scalar load
    float4 ev = *(const float4*)(base + (size_t)l * HH);
    a0 += w * ev.x; a1 += w * ev.y; a2 += w * ev.z; a3 += w * ev.w;
  }
  float4 o = {a0, a1, a2, a3};
  *(float4*)(part + ((size_t)(b * 32 + lc)) * HH + d0) = o;
}

__global__ void attn_red_k(const float* __restrict__ part, u16* __restrict__ cat2) {
  int idx = blockIdx.x * 256 + threadIdx.x;  // 65536
  int b = idx >> 10, d = idx & 1023;
  float s = 0.f;
#pragma unroll 8
  for (int lc = 0; lc < 32; ++lc) s += part[((size_t)(b * 32 + lc)) * HH + d];
  cat2[b * EH + EE + d] = f2b(s);
}

// ---- GRU gate fusion incl. 4-way k-split reduce + biases (torch order r,z,n)
__global__ void gates_k(const float* __restrict__ Ugi, const float* __restrict__ Ugh,
                        const float* __restrict__ bih, const float* __restrict__ bhh,
                        const float* __restrict__ hid, u16* __restrict__ nhbf,
                        float* __restrict__ outNh) {
  int idx = blockIdx.x * 256 + threadIdx.x;  // 65536
  int b = idx >> 10, j = idx & 1023;
  float gir = bih[j], giz = bih[HH + j], gin = bih[2 * HH + j];
  float ghr = bhh[j], ghz = bhh[HH + j], ghn = bhh[2 * HH + j];
#pragma unroll
  for (int k = 0; k < 4; ++k) {
    const float* pi = Ugi + ((size_t)(k * 64 + b)) * H3;
    const float* ph = Ugh + ((size_t)(k * 64 + b)) * H3;
    gir += pi[j]; giz += pi[HH + j]; gin += pi[2 * HH + j];
    ghr += ph[j]; ghz += ph[HH + j]; ghn += ph[2 * HH + j];
  }
  float r = 1.f / (1.f + __expf(-(gir + ghr)));
  float z = 1.f / (1.f + __expf(-(giz + ghz)));
  float n = tanhf(gin + r * ghn);
  float h = hid[idx];
  float v = (1.f - z) * n + z * h;
  nhbf[idx] = f2b(v);
  outNh[idx] = v;
}

// ---- two-phase logsumexp over V (fp32 logits in d_out)
__global__ void lse_part_k(const float* __restrict__ logits, float* __restrict__ pair) {
  int b = blockIdx.y, c = blockIdx.x, t = threadIdx.x;
  const float* row = logits + (size_t)b * VV;
  int v0 = c * CHUNK, v1 = min(VV, v0 + CHUNK);
  __shared__ float sd[256];
  float m = -1e30f;
  for (int v = v0 + t; v < v1; v += 256) m = fmaxf(m, row[v]);
  sd[t] = m; __syncthreads();
  for (int st = 128; st > 0; st >>= 1) { if (t < st) sd[t] = fmaxf(sd[t], sd[t + st]); __syncthreads(); }
  m = sd[0]; __syncthreads();
  float s = 0.f;
  for (int v = v0 + t; v < v1; v += 256) s += __expf(row[v] - m);
  sd[t] = s; __syncthreads();
  for (int st = 128; st > 0; st >>= 1) { if (t < st) sd[t] += sd[t + st]; __syncthreads(); }
  if (t == 0) { pair[(b * NCHUNK + c) * 2] = m; pair[(b * NCHUNK + c) * 2 + 1] = sd[0]; }
}

__global__ void lse2_k(const float* __restrict__ pair, float* __restrict__ lse) {
  int b = blockIdx.x;
  if (threadIdx.x == 0) {
    float M = -1e30f;
    for (int c = 0; c < NCHUNK; ++c) M = fmaxf(M, pair[(b * NCHUNK + c) * 2]);
    float S = 0.f;
    for (int c = 0; c < NCHUNK; ++c)
      S += pair[(b * NCHUNK + c) * 2 + 1] * __expf(pair[(b * NCHUNK + c) * 2] - M);
    lse[b] = M + logf(S);
  }
}

__global__ void final_k(float* __restrict__ logits, const float* __restrict__ lse) {
  int b = blockIdx.y;
  int v = blockIdx.x * 256 + threadIdx.x;
  if (v < VV) {
    size_t i = (size_t)b * VV + v;
    logits[i] = logits[i] - lse[b];
  }
}

extern "C" void kernel_launch(void* const* d_in, const int* in_sizes, int n_in,
                              void* d_out, int out_size, void* d_ws, size_t ws_size,
                              hipStream_t stream) {
  const int*   ids   = (const int*)d_in[0];
  const float* hid   = (const float*)d_in[1];
  const float* enc   = (const float*)d_in[2];
  const float* embW  = (const float*)d_in[3];
  const float* attnW = (const float*)d_in[4];
  const float* attnB = (const float*)d_in[5];
  const float* combW = (const float*)d_in[6];
  const float* combB = (const float*)d_in[7];
  const float* Wih   = (const float*)d_in[8];
  const float* Whh   = (const float*)d_in[9];
  const float* bih   = (const float*)d_in[10];
  const float* bhh   = (const float*)d_in[11];
  const float* outW  = (const float*)d_in[12];
  const float* outB  = (const float*)d_in[13];
  float* out_log = (float*)d_out;                  // [B,V] fp32
  float* out_nh  = out_log + (size_t)BB * VV;      // [B,H] fp32

  char* ws = (char*)d_ws;
  // region [0, 0x800000): time-shared: attn-score partials (4 MB) -> attn_applied
  // partials (8 MB) -> comb partials (4 MB) -> GRU partials (3 MB + 3 MB)
  float* U      = (float*)(ws);                // k-split partials / apart
  float* Ugh    = (float*)(ws + 0x300000);     // GRU hidden-GEMM partials (3 MB)
  u16*   cat1   = (u16*)  (ws + 0x800000);     // [64,2048] bf16
  u16*   cat2   = (u16*)  (ws + 0x840000);     // [64,2048] bf16
  u16*   hbf    = (u16*)  (ws + 0x880000);     // [64,1024] bf16
  float* aw     = (float*)(ws + 0x8A0000);     // [64,512]
  u16*   xbf    = (u16*)  (ws + 0x8C0000);     // [64,1024] bf16
  u16*   nhbf   = (u16*)  (ws + 0x8E0000);     // [64,1024] bf16
  float* pair   = (float*)(ws + 0x900000);     // [64,16,2]
  float* lse    = (float*)(ws + 0x902000);     // [64]

  // 1. gather + bf16 staging
  hipLaunchKernelGGL(prep_k, dim3(64), dim3(256), 0, stream, ids, embW, hid, cat1, cat2, hbf);
  // 2. attention scores: N=512, K=2048, WN=2, ksplit=32 (kpc=2) -> 128 blocks
  hipLaunchKernelGGL((gemm_k<2, 0>), dim3(4, 32), dim3(256), 0, stream,
                     cat1, attnW, U, (const float*)nullptr, 512, 2048, 2);
  // 3. fused reduce + bias + softmax over L
  hipLaunchKernelGGL(softmax_fused_k, dim3(64), dim3(256), 0, stream, U, attnB, aw);
  // 4-5. attn_applied = aw @ enc -> cat2[:, E:]  (2048 blocks, 16-deep pipe)
  hipLaunchKernelGGL(attn_part_k, dim3(2048), dim3(256), 0, stream, aw, enc, U);
  hipLaunchKernelGGL(attn_red_k, dim3(256), dim3(256), 0, stream, U, cat2);
  // 6-7. combine + relu: N=1024, K=2048, WN=2, ksplit=16 (kpc=4) -> 128 blocks
  hipLaunchKernelGGL((gemm_k<2, 0>), dim3(8, 16), dim3(256), 0, stream,
                     cat2, combW, U, (const float*)nullptr, 1024, 2048, 4);
  hipLaunchKernelGGL(reduce_k, dim3(256), dim3(256), 0, stream,
                     U, 16, 65536, 1024, combB, 1, (float*)nullptr, xbf);
  // 8. fused GRU matmuls: N=3072, K=1024, WN=2, ksplit=4 (kpc=8), z=2 -> 192 blocks
  hipLaunchKernelGGL(gru_gemm_k, dim3(24, 4, 2), dim3(256), 0, stream,
                     xbf, hbf, Wih, Whh, U, Ugh);
  // 9. gates (incl. 4-way reduce + biases) -> new_hidden (bf16 ws + fp32 out)
  hipLaunchKernelGGL(gates_k, dim3(256), dim3(256), 0, stream,
                     U, Ugh, bih, bhh, hid, nhbf, out_nh);
  // 10. vocab projection: N=50257, K=1024, WN=1 -> 786 blocks, fp32 logits + bias
  hipLaunchKernelGGL((gemm_k<1, 1>), dim3(786, 1), dim3(256), 0, stream,
                     nhbf, outW, out_log, outB, VV, 1024, 32);
  // 11-13. log_softmax: two-phase LSE then in-place subtract
  hipLaunchKernelGGL(lse_part_k, dim3(16, 64), dim3(256), 0, stream, out_log, pair);
  hipLaunchKernelGGL(lse2_k, dim3(64), dim3(64), 0, stream, pair, lse);
  hipLaunchKernelGGL(final_k, dim3(197, 64), dim3(256), 0, stream, out_log, lse);
}